// Round 1
// baseline (93.789 us; speedup 1.0000x reference)
//
#include <hip/hip_runtime.h>
#include <math.h>

#define KBT 2.494338785445972f
#define CH 8

struct F3 { float x, y, z; };
__device__ inline F3 f3sub(F3 a, F3 b) { return {a.x - b.x, a.y - b.y, a.z - b.z}; }
__device__ inline F3 f3cross(F3 a, F3 b) {
    return {a.y * b.z - a.z * b.y, a.z * b.x - a.x * b.z, a.x * b.y - a.y * b.x};
}
__device__ inline float f3dot(F3 a, F3 b) { return a.x * b.x + a.y * b.y + a.z * b.z; }
__device__ inline F3 ldp(const float* __restrict__ p, int i) {
    return {p[3 * i], p[3 * i + 1], p[3 * i + 2]};
}

// Kernel 1: features x = [cos(angles) (A), cos(dih) (D), sin(dih) (D)]
__global__ __launch_bounds__(256) void feat_kernel(
    const float* __restrict__ pos, const int* __restrict__ aidx,
    const int* __restrict__ didx, float* __restrict__ x, int A, int D) {
    int i = blockIdx.x * blockDim.x + threadIdx.x;
    if (i < A) {
        int i0 = aidx[3 * i], i1 = aidx[3 * i + 1], i2 = aidx[3 * i + 2];
        F3 p0 = ldp(pos, i0), p1 = ldp(pos, i1), p2 = ldp(pos, i2);
        F3 v0 = f3sub(p0, p1), v1 = f3sub(p2, p1);
        float d = f3dot(v0, v1);
        F3 c = f3cross(v0, v1);
        float r = sqrtf(d * d + f3dot(c, c));   // = |v0||v1|
        x[i] = d / r;                            // cos(atan2(|c|, d))
    } else if (i < A + D) {
        int j = i - A;
        int i0 = didx[4 * j], i1 = didx[4 * j + 1], i2 = didx[4 * j + 2], i3 = didx[4 * j + 3];
        F3 p0 = ldp(pos, i0), p1 = ldp(pos, i1), p2 = ldp(pos, i2), p3 = ldp(pos, i3);
        F3 b1v = f3sub(p1, p0), b2v = f3sub(p2, p1), b3v = f3sub(p3, p2);
        F3 n1 = f3cross(b1v, b2v), n2 = f3cross(b2v, b3v);
        float xc = f3dot(n1, n2);                          // cos-like term
        float b2n = sqrtf(f3dot(b2v, b2v));
        F3 cr = f3cross(n1, n2);
        float yc = f3dot(cr, b2v) / b2n;                   // sin-like term
        float r = sqrtf(xc * xc + yc * yc);
        x[A + j] = xc / r;        // cos(dihedral)
        x[A + D + j] = yc / r;    // sin(dihedral)
    }
}

// Kernel 2: y1 partials. grid = (H rows, CH chunks). No atomics.
__global__ __launch_bounds__(256) void w1_kernel(
    const float* __restrict__ W1, const float* __restrict__ x,
    float* __restrict__ partial, int F) {
    int r = blockIdx.x;
    int c = blockIdx.y;
    int F4 = F >> 2;
    const float4* __restrict__ row = (const float4*)(W1 + (size_t)r * F);
    const float4* __restrict__ xv = (const float4*)x;
    int per = (F4 + CH - 1) / CH;
    int s = c * per;
    int e = min(s + per, F4);
    float acc = 0.0f;
    for (int k = s + (int)threadIdx.x; k < e; k += 256) {
        float4 w = row[k];
        float4 v = xv[k];
        acc = fmaf(w.x, v.x, fmaf(w.y, v.y, fmaf(w.z, v.z, fmaf(w.w, v.w, acc))));
    }
    if (c == CH - 1) {  // scalar tail if F % 4 != 0 (not hit for F=299992)
        for (int k = (F4 << 2) + (int)threadIdx.x; k < F; k += 256)
            acc = fmaf(W1[(size_t)r * F + k], x[k], acc);
    }
    // wave reduce (64 lanes), then cross-wave via LDS
    #pragma unroll
    for (int off = 32; off; off >>= 1) acc += __shfl_down(acc, off);
    __shared__ float lds[4];
    int wave = threadIdx.x >> 6, lane = threadIdx.x & 63;
    if (lane == 0) lds[wave] = acc;
    __syncthreads();
    if (threadIdx.x == 0) partial[r * CH + c] = lds[0] + lds[1] + lds[2] + lds[3];
}

// Kernel 3: reduce partials + bias + tanh, layers 2/3, W4 dot, scale. One block.
__global__ __launch_bounds__(256) void tail_kernel(
    const float* __restrict__ partial, const float* __restrict__ b1,
    const float* __restrict__ W2, const float* __restrict__ b2,
    const float* __restrict__ W3, const float* __restrict__ b3,
    const float* __restrict__ W4, float* __restrict__ out) {
    __shared__ float xa[256];
    __shared__ float xb[256];
    int t = threadIdx.x;
    float s = 0.0f;
    #pragma unroll
    for (int c = 0; c < CH; ++c) s += partial[t * CH + c];
    xa[t] = tanhf(s + b1[t]);
    __syncthreads();

    const float4* __restrict__ W2v = (const float4*)W2;
    float acc = b2[t];
    #pragma unroll 8
    for (int k = 0; k < 64; ++k) {
        float4 w = W2v[t * 64 + k];
        acc += w.x * xa[4 * k] + w.y * xa[4 * k + 1] + w.z * xa[4 * k + 2] + w.w * xa[4 * k + 3];
    }
    xb[t] = tanhf(acc);
    __syncthreads();

    const float4* __restrict__ W3v = (const float4*)W3;
    acc = b3[t];
    #pragma unroll 8
    for (int k = 0; k < 64; ++k) {
        float4 w = W3v[t * 64 + k];
        acc += w.x * xb[4 * k] + w.y * xb[4 * k + 1] + w.z * xb[4 * k + 2] + w.w * xb[4 * k + 3];
    }
    float x3 = tanhf(acc);

    float v = W4[t] * x3;
    #pragma unroll
    for (int off = 32; off; off >>= 1) v += __shfl_down(v, off);
    __shared__ float lds[4];
    int wave = t >> 6, lane = t & 63;
    if (lane == 0) lds[wave] = v;
    __syncthreads();
    if (t == 0) out[0] = KBT * (lds[0] + lds[1] + lds[2] + lds[3]);
}

extern "C" void kernel_launch(void* const* d_in, const int* in_sizes, int n_in,
                              void* d_out, int out_size, void* d_ws, size_t ws_size,
                              hipStream_t stream) {
    const float* pos  = (const float*)d_in[0];
    const int*   aidx = (const int*)d_in[1];
    const int*   didx = (const int*)d_in[2];
    const float* W1   = (const float*)d_in[3];
    const float* b1   = (const float*)d_in[4];
    const float* W2   = (const float*)d_in[5];
    const float* b2   = (const float*)d_in[6];
    const float* W3   = (const float*)d_in[7];
    const float* b3   = (const float*)d_in[8];
    const float* W4   = (const float*)d_in[9];

    int A = in_sizes[1] / 3;
    int D = in_sizes[2] / 4;
    int F = A + 2 * D;

    float* ws = (float*)d_ws;
    float* x = ws;                              // F floats
    float* partial = ws + ((F + 3) & ~3);       // 256*CH floats

    int total = A + D;
    feat_kernel<<<(total + 255) / 256, 256, 0, stream>>>(pos, aidx, didx, x, A, D);

    dim3 g(256, CH);
    w1_kernel<<<g, 256, 0, stream>>>(W1, x, partial, F);

    tail_kernel<<<1, 256, 0, stream>>>(partial, b1, W2, b2, W3, b3, W4, (float*)d_out);
}

// Round 3
// 91.359 us; speedup vs baseline: 1.0266x; 1.0266x over previous
//
#include <hip/hip_runtime.h>
#include <math.h>

#define KBT 2.494338785445972f
#define CH 8

typedef float f4 __attribute__((ext_vector_type(4)));

struct F3 { float x, y, z; };
__device__ inline F3 f3sub(F3 a, F3 b) { return {a.x - b.x, a.y - b.y, a.z - b.z}; }
__device__ inline F3 f3cross(F3 a, F3 b) {
    return {a.y * b.z - a.z * b.y, a.z * b.x - a.x * b.z, a.x * b.y - a.y * b.x};
}
__device__ inline float f3dot(F3 a, F3 b) { return a.x * b.x + a.y * b.y + a.z * b.z; }
__device__ inline F3 ldp(const float* __restrict__ p, int i) {
    return {p[3 * i], p[3 * i + 1], p[3 * i + 2]};
}

// Kernel 1: features x = [cos(angles) (A), cos(dih) (D), sin(dih) (D)]
__global__ __launch_bounds__(256) void feat_kernel(
    const float* __restrict__ pos, const int* __restrict__ aidx,
    const int* __restrict__ didx, float* __restrict__ x, int A, int D) {
    int i = blockIdx.x * blockDim.x + threadIdx.x;
    if (i < A) {
        int i0 = aidx[3 * i], i1 = aidx[3 * i + 1], i2 = aidx[3 * i + 2];
        F3 p0 = ldp(pos, i0), p1 = ldp(pos, i1), p2 = ldp(pos, i2);
        F3 v0 = f3sub(p0, p1), v1 = f3sub(p2, p1);
        float d = f3dot(v0, v1);
        F3 c = f3cross(v0, v1);
        float r = sqrtf(d * d + f3dot(c, c));   // = |v0||v1|
        x[i] = d / r;                            // cos(atan2(|c|, d))
    } else if (i < A + D) {
        int j = i - A;
        int i0 = didx[4 * j], i1 = didx[4 * j + 1], i2 = didx[4 * j + 2], i3 = didx[4 * j + 3];
        F3 p0 = ldp(pos, i0), p1 = ldp(pos, i1), p2 = ldp(pos, i2), p3 = ldp(pos, i3);
        F3 b1v = f3sub(p1, p0), b2v = f3sub(p2, p1), b3v = f3sub(p3, p2);
        F3 n1 = f3cross(b1v, b2v), n2 = f3cross(b2v, b3v);
        float xc = f3dot(n1, n2);                          // cos-like term
        float b2n = sqrtf(f3dot(b2v, b2v));
        F3 cr = f3cross(n1, n2);
        float yc = f3dot(cr, b2v) / b2n;                   // sin-like term
        float r = sqrtf(xc * xc + yc * yc);
        x[A + j] = xc / r;        // cos(dihedral)
        x[A + D + j] = yc / r;    // sin(dihedral)
    }
}

// Kernel 2: y1 partials. grid = (H rows, CH chunks). No atomics.
// W1 loads are nontemporal (streamed once) to keep x / W2 / W3 L2-resident.
__global__ __launch_bounds__(256) void w1_kernel(
    const float* __restrict__ W1, const float* __restrict__ x,
    float* __restrict__ partial, int F) {
    int r = blockIdx.x;
    int c = blockIdx.y;
    int F4 = F >> 2;
    const f4* __restrict__ row = (const f4*)(W1 + (size_t)r * F);
    const f4* __restrict__ xv = (const f4*)x;
    int per = (F4 + CH - 1) / CH;
    int s = c * per;
    int e = min(s + per, F4);
    float acc = 0.0f;
    for (int k = s + (int)threadIdx.x; k < e; k += 256) {
        f4 w = __builtin_nontemporal_load(&row[k]);
        f4 v = xv[k];
        acc = fmaf(w.x, v.x, fmaf(w.y, v.y, fmaf(w.z, v.z, fmaf(w.w, v.w, acc))));
    }
    if (c == CH - 1) {  // scalar tail if F % 4 != 0 (not hit for F=299992)
        for (int k = (F4 << 2) + (int)threadIdx.x; k < F; k += 256)
            acc = fmaf(W1[(size_t)r * F + k], x[k], acc);
    }
    // wave reduce (64 lanes), then cross-wave via LDS
    #pragma unroll
    for (int off = 32; off; off >>= 1) acc += __shfl_down(acc, off);
    __shared__ float lds[4];
    int wave = threadIdx.x >> 6, lane = threadIdx.x & 63;
    if (lane == 0) lds[wave] = acc;
    __syncthreads();
    if (threadIdx.x == 0) partial[r * CH + c] = lds[0] + lds[1] + lds[2] + lds[3];
}

// Kernel 3: reduce partials + bias + tanh, layers 2/3, W4 dot, scale.
// One block of 1024 threads (16 waves): 4 threads per row on layers 2/3
// for 4x the memory-level parallelism of the previous 256-thread version.
__global__ __launch_bounds__(1024) void tail_kernel(
    const float* __restrict__ partial, const float* __restrict__ b1,
    const float* __restrict__ W2, const float* __restrict__ b2,
    const float* __restrict__ W3, const float* __restrict__ b3,
    const float* __restrict__ W4, float* __restrict__ out) {
    __shared__ float xa[256];
    __shared__ float xb[256];
    __shared__ float red[1024];
    __shared__ float lds4[16];
    int t = threadIdx.x;
    int row = t >> 2, part = t & 3;

    // stage 1: finish layer 1 (threads 0..255)
    if (t < 256) {
        float s = 0.0f;
        #pragma unroll
        for (int c = 0; c < CH; ++c) s += partial[t * CH + c];
        xa[t] = tanhf(s + b1[t]);
    }
    __syncthreads();

    // layer 2: thread (row,part) covers 64 floats of row `row`
    {
        const f4* __restrict__ W2v = (const f4*)W2 + (row << 6) + (part << 4);
        float acc = 0.0f;
        #pragma unroll
        for (int k = 0; k < 16; ++k) {
            f4 w = W2v[k];
            int base = (part << 6) + (k << 2);
            acc += w.x * xa[base] + w.y * xa[base + 1] + w.z * xa[base + 2] + w.w * xa[base + 3];
        }
        red[t] = acc;
    }
    __syncthreads();
    if (t < 256)
        xb[t] = tanhf(red[4 * t] + red[4 * t + 1] + red[4 * t + 2] + red[4 * t + 3] + b2[t]);
    __syncthreads();

    // layer 3
    {
        const f4* __restrict__ W3v = (const f4*)W3 + (row << 6) + (part << 4);
        float acc = 0.0f;
        #pragma unroll
        for (int k = 0; k < 16; ++k) {
            f4 w = W3v[k];
            int base = (part << 6) + (k << 2);
            acc += w.x * xb[base] + w.y * xb[base + 1] + w.z * xb[base + 2] + w.w * xb[base + 3];
        }
        red[t] = acc;
    }
    __syncthreads();

    // output: x3 = tanh(...); v = W4 .* x3; reduce 256 -> scalar
    float v = 0.0f;
    if (t < 256) {
        float x3 = tanhf(red[4 * t] + red[4 * t + 1] + red[4 * t + 2] + red[4 * t + 3] + b3[t]);
        v = W4[t] * x3;
    }
    #pragma unroll
    for (int off = 32; off; off >>= 1) v += __shfl_down(v, off);
    if ((t & 63) == 0) lds4[t >> 6] = v;
    __syncthreads();
    if (t == 0) out[0] = KBT * (lds4[0] + lds4[1] + lds4[2] + lds4[3]);
}

extern "C" void kernel_launch(void* const* d_in, const int* in_sizes, int n_in,
                              void* d_out, int out_size, void* d_ws, size_t ws_size,
                              hipStream_t stream) {
    const float* pos  = (const float*)d_in[0];
    const int*   aidx = (const int*)d_in[1];
    const int*   didx = (const int*)d_in[2];
    const float* W1   = (const float*)d_in[3];
    const float* b1   = (const float*)d_in[4];
    const float* W2   = (const float*)d_in[5];
    const float* b2   = (const float*)d_in[6];
    const float* W3   = (const float*)d_in[7];
    const float* b3   = (const float*)d_in[8];
    const float* W4   = (const float*)d_in[9];

    int A = in_sizes[1] / 3;
    int D = in_sizes[2] / 4;
    int F = A + 2 * D;

    float* ws = (float*)d_ws;
    float* x = ws;                              // F floats
    float* partial = ws + ((F + 3) & ~3);       // 256*CH floats

    int total = A + D;
    feat_kernel<<<(total + 255) / 256, 256, 0, stream>>>(pos, aidx, didx, x, A, D);

    dim3 g(256, CH);
    w1_kernel<<<g, 256, 0, stream>>>(W1, x, partial, F);

    tail_kernel<<<1, 1024, 0, stream>>>(partial, b1, W2, b2, W3, b3, W4, (float*)d_out);
}